// Round 1
// baseline (895.261 us; speedup 1.0000x reference)
//
#include <hip/hip_runtime.h>
#include <math.h>

#define NG 8     // groups per block (half-wave per group)
#define NSRC 10  // N
#define DIM 32   // D

__launch_bounds__(256)
__global__ void attn2d_kernel(
    const float* __restrict__ q, const float* __restrict__ k,
    const float* __restrict__ pos, const int* __restrict__ mask,
    const float* __restrict__ Wq, const float* __restrict__ Wk,
    const float* __restrict__ Wv,
    const float* __restrict__ pW1, const float* __restrict__ pb1,
    const float* __restrict__ pW2, const float* __restrict__ pb2,
    const float* __restrict__ aW1, const float* __restrict__ ab1,
    const float* __restrict__ aW2, const float* __restrict__ ab2,
    const float* __restrict__ oW, const float* __restrict__ ob,
    float* __restrict__ out_x, float* __restrict__ out_attn,
    float* __restrict__ out_std, float* __restrict__ out_nks)
{
    // packed (Wq,Wk,Wv,oW)[e*32+d]
    __shared__ float4 Wc[1024];           // 16 KB
    __shared__ float4 kb4[NG * NSRC * 8]; // 10 KB  (k staging; reused for scores)
    __shared__ float4 qb4[NG * 8];        // 1 KB
    __shared__ float4 posb[NG * NSRC];    // 1.25 KB
    __shared__ int    mb[NG * NSRC];
    __shared__ float4 pw1c[4];            // pW1 columns
    __shared__ float  pb1b[4];
    __shared__ float4 pw2t[32];           // pW2 column d as float4 over h
    __shared__ float  pb2b[32];
    __shared__ float4 aw1col[32];         // [h][c] : aW1[4c..4c+3][h]
    __shared__ float  ab1b[4];
    __shared__ float4 aw2t[32];           // aW2 column d as float4 over h
    __shared__ float  ab2b[32];
    __shared__ float  obb[32];
    __shared__ float4 ub4[NG * NSRC];     // relu(u)[g][n] over h
    __shared__ float  yb[NG * DIM];       // (vp+pe)*attn summed over n

    const int tid = threadIdx.x;
    const int gb  = tid >> 5;   // group in block
    const int d   = tid & 31;   // channel
    const long long G0 = (long long)blockIdx.x * NG + gb;

    // ---------------- staging ----------------
    {
        const float4* kg4 = (const float4*)k;
        const long long kbase = (long long)blockIdx.x * (NG * NSRC * 8);
        #pragma unroll
        for (int r = 0; r < 3; ++r) {
            int i = tid + r * 256;
            if (i < NG * NSRC * 8) kb4[i] = kg4[kbase + i];
        }
        if (tid < NG * 8)
            qb4[tid] = ((const float4*)q)[(long long)blockIdx.x * NG * 8 + tid];
        if (tid < NG * NSRC) {
            posb[tid] = ((const float4*)pos)[(long long)blockIdx.x * NG * NSRC + tid];
            mb[tid]   = mask[(long long)blockIdx.x * NG * NSRC + tid];
        }
        #pragma unroll
        for (int r = 0; r < 4; ++r) {
            int i = tid + r * 256;  // i = e*32 + dd
            Wc[i] = make_float4(Wq[i], Wk[i], Wv[i], oW[i]);
        }
        if (tid < 4) {
            pw1c[tid] = make_float4(pW1[0*4+tid], pW1[1*4+tid], pW1[2*4+tid], pW1[3*4+tid]);
            pb1b[tid] = pb1[tid];
            ab1b[tid] = ab1[tid];
        }
        if (tid < 32) {
            pw2t[tid] = make_float4(pW2[0*32+tid], pW2[1*32+tid], pW2[2*32+tid], pW2[3*32+tid]);
            pb2b[tid] = pb2[tid];
            aw2t[tid] = make_float4(aW2[0*32+tid], aW2[1*32+tid], aW2[2*32+tid], aW2[3*32+tid]);
            ab2b[tid] = ab2[tid];
            obb[tid]  = ob[tid];
            int h = tid >> 3, c = tid & 7;
            aw1col[tid] = make_float4(aW1[(4*c+0)*4+h], aW1[(4*c+1)*4+h],
                                      aW1[(4*c+2)*4+h], aW1[(4*c+3)*4+h]);
        }
    }
    __syncthreads();

    // per-lane small weights
    const float4 pw1r0 = pw1c[0], pw1r1 = pw1c[1], pw1r2 = pw1c[2], pw1r3 = pw1c[3];
    const float pb10 = pb1b[0], pb11 = pb1b[1], pb12 = pb1b[2], pb13 = pb1b[3];
    const float4 pw2d = pw2t[d]; const float pb2d = pb2b[d];
    const float4 aw2d = aw2t[d]; const float ab2d = ab2b[d];
    const float obd = obb[d];

    // ---------------- Phase A: q/k/v projections ----------------
    float qp = 0.f;
    float kp[NSRC], vp[NSRC];
    #pragma unroll
    for (int n = 0; n < NSRC; ++n) { kp[n] = 0.f; vp[n] = 0.f; }

    #pragma unroll
    for (int c = 0; c < 8; ++c) {
        float4 w0 = Wc[(4*c+0)*32 + d];
        float4 w1 = Wc[(4*c+1)*32 + d];
        float4 w2 = Wc[(4*c+2)*32 + d];
        float4 w3 = Wc[(4*c+3)*32 + d];
        float4 q4 = qb4[gb*8 + c];
        qp += q4.x*w0.x + q4.y*w1.x + q4.z*w2.x + q4.w*w3.x;
        #pragma unroll
        for (int n = 0; n < NSRC; ++n) {
            float4 kk = kb4[(gb*NSRC+n)*8 + c];
            kp[n] += kk.x*w0.y + kk.y*w1.y + kk.z*w2.y + kk.w*w3.y;
            vp[n] += kk.x*w0.z + kk.y*w1.z + kk.z*w2.z + kk.w*w3.z;
        }
    }

    // ---------------- Phase B: mask + k statistics ----------------
    unsigned vbits = 0; int cnt = 0;
    #pragma unroll
    for (int n = 0; n < NSRC; ++n) {
        int m = mb[gb*NSRC + n];
        vbits |= (unsigned)(m != 0) << n;
        cnt += (m != 0);
    }
    if (cnt == 0) { vbits = (1u << NSRC) - 1u; cnt = NSRC; }
    float wv[NSRC];
    #pragma unroll
    for (int n = 0; n < NSRC; ++n) wv[n] = (float)((vbits >> n) & 1u);

    const float cntf = (float)cnt;
    const float rc = 1.f / cntf;
    float mean = 0.f, mabs = 0.f;
    #pragma unroll
    for (int n = 0; n < NSRC; ++n) { mean += wv[n]*kp[n]; mabs += wv[n]*fabsf(kp[n]); }
    mean *= rc; mabs *= rc;
    float var = 0.f;
    #pragma unroll
    for (int n = 0; n < NSRC; ++n) { float dd = kp[n]-mean; var += wv[n]*dd*dd; }
    var *= 1.f / fmaxf(cntf - 1.f, 1.f);
    const float stdv = (cnt == 1) ? 0.f : sqrtf(var);
    const float nksv = (cnt == 1) ? 0.f : stdv / (mabs + 1e-6f);

    // ---------------- Phase C: positional MLP ----------------
    float pe[NSRC];
    #pragma unroll
    for (int n = 0; n < NSRC; ++n) {
        float4 p4 = posb[gb*NSRC + n];
        float t0 = fmaxf(pb10 + p4.x*pw1r0.x + p4.y*pw1r0.y + p4.z*pw1r0.z + p4.w*pw1r0.w, 0.f);
        float t1 = fmaxf(pb11 + p4.x*pw1r1.x + p4.y*pw1r1.y + p4.z*pw1r1.z + p4.w*pw1r1.w, 0.f);
        float t2 = fmaxf(pb12 + p4.x*pw1r2.x + p4.y*pw1r2.y + p4.z*pw1r2.z + p4.w*pw1r2.w, 0.f);
        float t3 = fmaxf(pb13 + p4.x*pw1r3.x + p4.y*pw1r3.y + p4.z*pw1r3.z + p4.w*pw1r3.w, 0.f);
        pe[n] = pb2d + t0*pw2d.x + t1*pw2d.y + t2*pw2d.z + t3*pw2d.w;
    }

    // ---------------- Phase D: score MLP hidden (cross-lane via LDS) ----------------
    float* scb = (float*)kb4;  // reuse k staging (same wave -> ordered)
    #pragma unroll
    for (int n = 0; n < NSRC; ++n)
        scb[(gb*NSRC + n)*DIM + d] = kp[n] - qp + pe[n];

    {
        const float4* scb4 = (const float4*)kb4;
        float* ub = (float*)ub4;
        int n = d >> 2, h = d & 3;
        float u = ab1b[h];
        #pragma unroll
        for (int c = 0; c < 8; ++c) {
            float4 s4 = scb4[(gb*NSRC + n)*8 + c];
            float4 a4 = aw1col[h*8 + c];
            u += s4.x*a4.x + s4.y*a4.y + s4.z*a4.z + s4.w*a4.w;
        }
        ub[gb*NSRC*4 + n*4 + h] = fmaxf(u, 0.f);
        if (d < 8) {
            int n2 = 8 + (d >> 2);
            float u2 = ab1b[h];
            #pragma unroll
            for (int c = 0; c < 8; ++c) {
                float4 s4 = scb4[(gb*NSRC + n2)*8 + c];
                float4 a4 = aw1col[h*8 + c];
                u2 += s4.x*a4.x + s4.y*a4.y + s4.z*a4.z + s4.w*a4.w;
            }
            ub[gb*NSRC*4 + n2*4 + h] = fmaxf(u2, 0.f);
        }
    }

    // ---------------- Phase E: scores + masked softmax over n ----------------
    float at[NSRC];
    #pragma unroll
    for (int n = 0; n < NSRC; ++n) {
        float4 r4 = ub4[gb*NSRC + n];
        float s = ab2d + r4.x*aw2d.x + r4.y*aw2d.y + r4.z*aw2d.z + r4.w*aw2d.w;
        at[n] = ((vbits >> n) & 1u) ? s : -INFINITY;
    }
    float mx = at[0];
    #pragma unroll
    for (int n = 1; n < NSRC; ++n) mx = fmaxf(mx, at[n]);
    float ssum = 0.f;
    #pragma unroll
    for (int n = 0; n < NSRC; ++n) { float e = __expf(at[n]-mx); at[n] = e; ssum += e; }
    const float rs = 1.f / ssum;
    #pragma unroll
    for (int n = 0; n < NSRC; ++n) at[n] *= rs;

    // ---------------- Phase F: output projection ----------------
    float y = 0.f;
    #pragma unroll
    for (int n = 0; n < NSRC; ++n) y += (vp[n] + pe[n]) * at[n];
    yb[gb*DIM + d] = y;
    {
        const float4* yb4 = (const float4*)yb;
        float x = obd;
        #pragma unroll
        for (int c = 0; c < 8; ++c) {
            float4 w0 = Wc[(4*c+0)*32 + d];
            float4 w1 = Wc[(4*c+1)*32 + d];
            float4 w2 = Wc[(4*c+2)*32 + d];
            float4 w3 = Wc[(4*c+3)*32 + d];
            float4 y4 = yb4[gb*8 + c];
            x += y4.x*w0.w + y4.y*w1.w + y4.z*w2.w + y4.w*w3.w;
        }
        out_x[G0*DIM + d] = x;
    }

    // ---------------- stores ----------------
    out_std[G0*DIM + d] = stdv;
    out_nks[G0*DIM + d] = nksv;
    const long long abase = G0*(NSRC*DIM) + d;
    #pragma unroll
    for (int n = 0; n < NSRC; ++n) out_attn[abase + n*DIM] = at[n];
}

extern "C" void kernel_launch(void* const* d_in, const int* in_sizes, int n_in,
                              void* d_out, int out_size, void* d_ws, size_t ws_size,
                              hipStream_t stream) {
    const float* q    = (const float*)d_in[0];
    const float* k    = (const float*)d_in[1];
    const float* pos  = (const float*)d_in[2];
    const int*   mask = (const int*)  d_in[3];
    const float* Wq   = (const float*)d_in[4];
    const float* Wk   = (const float*)d_in[5];
    const float* Wv   = (const float*)d_in[6];
    const float* pW1  = (const float*)d_in[7];
    const float* pb1  = (const float*)d_in[8];
    const float* pW2  = (const float*)d_in[9];
    const float* pb2  = (const float*)d_in[10];
    const float* aW1  = (const float*)d_in[11];
    const float* ab1  = (const float*)d_in[12];
    const float* aW2  = (const float*)d_in[13];
    const float* ab2  = (const float*)d_in[14];
    const float* oW   = (const float*)d_in[15];
    const float* ob   = (const float*)d_in[16];

    const int G = in_sizes[0] / DIM;          // R*S = 131072 groups
    const int blocks = G / NG;                // 16384

    float* out_x    = (float*)d_out;
    float* out_attn = out_x + (long long)G * DIM;
    float* out_std  = out_attn + (long long)G * NSRC * DIM;
    float* out_nks  = out_std + (long long)G * DIM;

    attn2d_kernel<<<blocks, 256, 0, stream>>>(
        q, k, pos, mask, Wq, Wk, Wv, pW1, pb1, pW2, pb2,
        aW1, ab1, aW2, ab2, oW, ob,
        out_x, out_attn, out_std, out_nks);
}